// Round 5
// baseline (372.327 us; speedup 1.0000x reference)
//
#include <hip/hip_runtime.h>
#include <cstdint>
#include <cstddef>

#define TDIM 4096       // B*S tokens
#define DDIM 1024
#define HDIM 4096
#define EDIM 8
#define CAPD 2048
#define NSLOT 8192      // T*K
#define NROUTERBLK 1024

typedef _Float16 f16;
typedef _Float16 f16x2 __attribute__((ext_vector_type(2)));
typedef _Float16 f16x4 __attribute__((ext_vector_type(4)));
typedef _Float16 f16x8 __attribute__((ext_vector_type(8)));
typedef float f32x4 __attribute__((ext_vector_type(4)));

__device__ __forceinline__ void gload16(const void* g, void* l) {
  __builtin_amdgcn_global_load_lds(
      (const __attribute__((address_space(1))) unsigned int*)g,
      (__attribute__((address_space(3))) unsigned int*)l, 16, 0, 0);
}

__device__ __forceinline__ float gelu_fast(float x) {
  float y = 1.5957691216057308f * (x + 0.044715f * x * x * x);
  y = fminf(y, 60.f);
  float e = __expf(y);
  return x * e * __builtin_amdgcn_rcpf(e + 1.f);
}

#define MEMFENCE asm volatile("" ::: "memory")

// ---------------- transpose + f32->f16 convert: src (E,R,C) -> dst (E,C,R) ----------------
__global__ __launch_bounds__(256)
void transpose_cvt(const float* __restrict__ src, f16* __restrict__ dst, int R, int C) {
  __shared__ float tile[64][65];
  const int e = blockIdx.z;
  const int c0 = blockIdx.x * 64, r0 = blockIdx.y * 64;
  const int tid = threadIdx.x;
  const float* s = src + (size_t)e * R * C;
  f16* d = dst + (size_t)e * R * C;
  #pragma unroll
  for (int p = 0; p < 4; ++p) {
    const int row = p * 16 + (tid >> 4);
    const int col = (tid & 15) * 4;
    float4 v = *(const float4*)(s + (size_t)(r0 + row) * C + c0 + col);
    tile[row][col] = v.x; tile[row][col + 1] = v.y;
    tile[row][col + 2] = v.z; tile[row][col + 3] = v.w;
  }
  __syncthreads();
  #pragma unroll
  for (int p = 0; p < 4; ++p) {
    const int crow = p * 16 + (tid >> 4);
    const int q = (tid & 15) * 4;
    f16x4 o;
    #pragma unroll
    for (int j = 0; j < 4; ++j) o[j] = (f16)tile[q + j][crow];
    *(f16x4*)(d + (size_t)(c0 + crow) * R + r0 + q) = o;
  }
}

// ---------------- router ----------------
__global__ void router_k(const float* __restrict__ x, const float* __restrict__ rw,
                         int* __restrict__ eidx, float* __restrict__ gates,
                         float* __restrict__ bps) {
  __shared__ float lrw[EDIM * DDIM];
  __shared__ float wps[4][EDIM];
  const int tid = threadIdx.x, lane = tid & 63, wv = tid >> 6;
  for (int i = tid; i < EDIM * DDIM; i += 256) lrw[i] = rw[i];
  __syncthreads();
  const int t = blockIdx.x * 4 + wv;
  float acc[EDIM];
  #pragma unroll
  for (int e = 0; e < EDIM; ++e) acc[e] = 0.f;
  const float* xr = x + (size_t)t * DDIM;
  #pragma unroll
  for (int j = 0; j < DDIM / 64; ++j) {
    float xv = xr[j * 64 + lane];
    #pragma unroll
    for (int e = 0; e < EDIM; ++e) acc[e] += xv * lrw[e * DDIM + j * 64 + lane];
  }
  #pragma unroll
  for (int off = 32; off >= 1; off >>= 1) {
    #pragma unroll
    for (int e = 0; e < EDIM; ++e) acc[e] += __shfl_xor(acc[e], off);
  }
  float mx = acc[0];
  #pragma unroll
  for (int e = 1; e < EDIM; ++e) mx = fmaxf(mx, acc[e]);
  float p[EDIM], s = 0.f;
  #pragma unroll
  for (int e = 0; e < EDIM; ++e) { p[e] = expf(acc[e] - mx); s += p[e]; }
  float inv = 1.f / s;
  #pragma unroll
  for (int e = 0; e < EDIM; ++e) p[e] *= inv;
  int i1 = 0; float p1 = p[0];
  #pragma unroll
  for (int e = 1; e < EDIM; ++e) if (p[e] > p1) { p1 = p[e]; i1 = e; }
  int i2 = (i1 == 0) ? 1 : 0; float p2 = p[i2];
  #pragma unroll
  for (int e = 0; e < EDIM; ++e) if (e != i1 && p[e] > p2) { p2 = p[e]; i2 = e; }
  float gs = 1.f / (p1 + p2);
  if (lane == 0) {
    eidx[2 * t] = i1; eidx[2 * t + 1] = i2;
    gates[2 * t] = p1 * gs; gates[2 * t + 1] = p2 * gs;
    #pragma unroll
    for (int e = 0; e < EDIM; ++e) wps[wv][e] = p[e];
  }
  __syncthreads();
  if (tid < EDIM)
    bps[blockIdx.x * EDIM + tid] = wps[0][tid] + wps[1][tid] + wps[2][tid] + wps[3][tid];
}

// ---------------- per-chunk expert histogram ----------------
__global__ void count_k(const int* __restrict__ eidx, int* __restrict__ cc) {
  __shared__ int h[EDIM];
  const int tid = threadIdx.x;
  if (tid < EDIM) h[tid] = 0;
  __syncthreads();
  atomicAdd(&h[eidx[blockIdx.x * 256 + tid]], 1);
  __syncthreads();
  if (tid < EDIM) cc[blockIdx.x * EDIM + tid] = h[tid];
}

// ---------------- scan chunks, totals, lb_loss ----------------
__global__ void scan_k(const int* __restrict__ cc, const float* __restrict__ bps,
                       int* __restrict__ cb, int* __restrict__ counts,
                       int* __restrict__ rowsNeeded, float* __restrict__ lb_out) {
  __shared__ float red[32][EDIM];
  __shared__ int cnt_s[EDIM];
  const int tid = threadIdx.x;
  const int e = tid & 7, g = tid >> 3;
  float s = 0.f;
  for (int j = 0; j < 32; ++j) s += bps[(g + 32 * j) * EDIM + e];
  red[g][e] = s;
  __syncthreads();
  for (int st = 16; st >= 1; st >>= 1) {
    if (g < st) red[g][e] += red[g + st][e];
    __syncthreads();
  }
  if (tid < EDIM) {
    int base = 0;
    for (int c = 0; c < 32; ++c) { cb[c * EDIM + tid] = base; base += cc[c * EDIM + tid]; }
    counts[tid] = base;
    rowsNeeded[tid] = base < CAPD ? base : CAPD;
    cnt_s[tid] = base;
  }
  __syncthreads();
  if (tid == 0) {
    float lb = 0.f;
    for (int ee = 0; ee < EDIM; ++ee)
      lb += (red[0][ee] / (float)TDIM) * ((float)cnt_s[ee] / (float)NSLOT);
    lb_out[0] = lb * (float)EDIM;
  }
}

// ---------------- per-slot position via wave ballots (deterministic) ----------------
__global__ void pos_k(const int* __restrict__ eidx, const float* __restrict__ gates,
                      const int* __restrict__ cb, int* __restrict__ posa,
                      float* __restrict__ wslot) {
  __shared__ int wcnt[4][EDIM];
  const int tid = threadIdx.x, lane = tid & 63, wv = tid >> 6;
  const int slot = blockIdx.x * 256 + tid;
  const int e = eidx[slot];
  const unsigned long long below = (1ull << lane) - 1ull;
  int wavepos = 0;
  #pragma unroll
  for (int ee = 0; ee < EDIM; ++ee) {
    unsigned long long m = __ballot(e == ee);
    if (lane == 0) wcnt[wv][ee] = __popcll(m);
    if (e == ee) wavepos = __popcll(m & below);
  }
  __syncthreads();
  int off = 0;
  for (int w = 0; w < wv; ++w) off += wcnt[w][e];
  const int pos = cb[blockIdx.x * EDIM + e] + off + wavepos;
  posa[slot] = pos;
  wslot[slot] = (pos < CAPD) ? gates[slot] : 0.f;
}

// ---------------- scatter token rows -> f16 expert buffers ----------------
__global__ void scatter_k(const float* __restrict__ x, const int* __restrict__ eidx,
                          const int* __restrict__ posa, f16* __restrict__ buf) {
  const int s = blockIdx.x, lane = threadIdx.x;
  const int p = posa[s];
  if (p >= CAPD) return;
  const int e = eidx[s], tok = s >> 1;
  const float4* src = (const float4*)(x + (size_t)tok * DDIM);
  f16x4* dst = (f16x4*)(buf + ((size_t)e * CAPD + p) * DDIM);
  #pragma unroll
  for (int j = 0; j < DDIM / 4 / 64; ++j) {
    float4 v = src[j * 64 + lane];
    f16x4 o; o.x = (f16)v.x; o.y = (f16)v.y; o.z = (f16)v.z; o.w = (f16)v.w;
    dst[j * 64 + lane] = o;
  }
}

// ============ 256x256 f16 MFMA GEMM, phase-split dbuf schedule (T2+T3+T4+T5) ============
// B pre-transposed (N,LD). Grid: x=nt, y=z (e + EDIM*ks), z=mt (SLOWEST: work-first order
// so early-exit blocks trail and every CU gets one live block before any CU gets two).
// 8 waves (2M x 4N), per-wave 128x64 output. LDS 128KB = 2 dbuf x (A 32KB + B 32KB).
// T2 swizzle: LDS linear dest, inverse-swizzled global src, swizzled reads (slot ^= row&7).
template<int KLEN, int LD, int N, int GELU>
__global__ __launch_bounds__(512, 1)
void gemm256(const f16* __restrict__ A, const f16* __restrict__ Bt,
             const float* __restrict__ bias, f16* __restrict__ C, size_t pstride,
             const int* __restrict__ rowsNeeded) {
  constexpr int NKT = KLEN / 64;
  __shared__ f16 smem[4 * 16384];          // A0 | B0 | A1 | B1, 32KB each
  const int z = blockIdx.y, e = z & 7, ks = z >> 3;
  const int mt = blockIdx.z, nt = blockIdx.x;
  if (mt * 256 >= rowsNeeded[e]) return;
  const int tid = threadIdx.x, lane = tid & 63, wv = tid >> 6;
  const int wr = wv >> 2, wc = wv & 3;     // 2 x 4 wave grid
  f16* const As0 = smem;
  f16* const Bs0 = smem + 16384;
  f16* const As1 = smem + 2 * 16384;
  f16* const Bs1 = smem + 3 * 16384;
  const size_t abase = ((size_t)e * CAPD + (size_t)mt * 256) * LD + (size_t)ks * KLEN;
  const size_t bbase = ((size_t)e * N + (size_t)nt * 256) * LD + (size_t)ks * KLEN;

  // staging: chunk idx = i*512+tid covers LDS bytes idx*16; row=idx>>3, slot=idx&7.
  // global src column pre-swizzled: (slot ^ (row&7))*8  (involution; read undoes it)
  const f16* aSrcB[4]; const f16* bSrcB[4];
  #pragma unroll
  for (int i = 0; i < 4; ++i) {
    const int idx = i * 512 + tid, row = idx >> 3, slot = idx & 7;
    aSrcB[i] = A + abase + (size_t)row * LD + (slot ^ (row & 7)) * 8;
    bSrcB[i] = Bt + bbase + (size_t)row * LD + (slot ^ (row & 7)) * 8;
  }
  const int ldsOff = wv * 1024;            // wave-uniform byte base (lane*16 added by HW)

  const int ro = lane & 15, q4 = (lane >> 4) * 4, ko0 = (lane >> 4) * 8;

  f32x4 acc[8][4];
  #pragma unroll
  for (int m = 0; m < 8; ++m)
    #pragma unroll
    for (int n = 0; n < 4; ++n) acc[m][n] = (f32x4){0.f, 0.f, 0.f, 0.f};

  // ---- prologue: stage tiles 0 and 1
  #pragma unroll
  for (int i = 0; i < 4; ++i) gload16(aSrcB[i], (char*)As0 + i * 8192 + ldsOff);
  #pragma unroll
  for (int i = 0; i < 4; ++i) gload16(bSrcB[i], (char*)Bs0 + i * 8192 + ldsOff);
  #pragma unroll
  for (int i = 0; i < 4; ++i) gload16(aSrcB[i] + 64, (char*)As1 + i * 8192 + ldsOff);
  #pragma unroll
  for (int i = 0; i < 4; ++i) gload16(bSrcB[i] + 64, (char*)Bs1 + i * 8192 + ldsOff);
  asm volatile("s_waitcnt vmcnt(8)" ::: "memory");   // tile 0 landed (per-wave)
  __builtin_amdgcn_s_barrier(); MEMFENCE;            // all waves' tile-0 writes visible

  // swizzled frag read: row r, k element k0 (multiple of 8)
  auto ldfrag = [&](const f16* base, int r, int k0) -> f16x8 {
    return *(const f16x8*)((const char*)base + r * 128 + ((k0 * 2) ^ ((r & 7) << 4)));
  };

  int cur = 0;
  #pragma unroll 1
  for (int kt = 0; kt < NKT; ++kt) {
    const f16* Ab = cur ? As1 : As0;
    const f16* Bb = cur ? Bs1 : Bs0;
    f16x8 af[4][2], bf0[2][2], bf1[2][2];
    // ---- P1: read A-half0 + B-half0; MFMA quadrant (m0-3, n0-1)
    #pragma unroll
    for (int m = 0; m < 4; ++m)
      #pragma unroll
      for (int k = 0; k < 2; ++k) af[m][k] = ldfrag(Ab, wr * 128 + m * 16 + ro, k * 32 + ko0);
    #pragma unroll
    for (int n = 0; n < 2; ++n)
      #pragma unroll
      for (int k = 0; k < 2; ++k) bf0[n][k] = ldfrag(Bb, wc * 64 + n * 16 + ro, k * 32 + ko0);
    __builtin_amdgcn_s_barrier();
    asm volatile("s_waitcnt lgkmcnt(0)" ::: "memory");
    __builtin_amdgcn_s_setprio(1);
    #pragma unroll
    for (int m = 0; m < 4; ++m)
      #pragma unroll
      for (int n = 0; n < 2; ++n)
        #pragma unroll
        for (int k = 0; k < 2; ++k)
          acc[m][n] = __builtin_amdgcn_mfma_f32_16x16x32_f16(af[m][k], bf0[n][k], acc[m][n], 0, 0, 0);
    __builtin_amdgcn_s_setprio(0);
    __builtin_amdgcn_s_barrier(); MEMFENCE;
    // ---- P2: read B-half1; MFMA quadrant (m0-3, n2-3)
    #pragma unroll
    for (int n = 0; n < 2; ++n)
      #pragma unroll
      for (int k = 0; k < 2; ++k) bf1[n][k] = ldfrag(Bb, wc * 64 + 32 + n * 16 + ro, k * 32 + ko0);
    __builtin_amdgcn_s_barrier();
    asm volatile("s_waitcnt lgkmcnt(0)" ::: "memory");
    __builtin_amdgcn_s_setprio(1);
    #pragma unroll
    for (int m = 0; m < 4; ++m)
      #pragma unroll
      for (int n = 0; n < 2; ++n)
        #pragma unroll
        for (int k = 0; k < 2; ++k)
          acc[m][2 + n] = __builtin_amdgcn_mfma_f32_16x16x32_f16(af[m][k], bf1[n][k], acc[m][2 + n], 0, 0, 0);
    __builtin_amdgcn_s_setprio(0);
    __builtin_amdgcn_s_barrier(); MEMFENCE;
    // ---- P3: read A-half1 (reuse af regs); MFMA quadrant (m4-7, n2-3)
    #pragma unroll
    for (int m = 0; m < 4; ++m)
      #pragma unroll
      for (int k = 0; k < 2; ++k) af[m][k] = ldfrag(Ab, wr * 128 + 64 + m * 16 + ro, k * 32 + ko0);
    __builtin_amdgcn_s_barrier();
    asm volatile("s_waitcnt lgkmcnt(0)" ::: "memory");
    __builtin_amdgcn_s_setprio(1);
    #pragma unroll
    for (int m = 0; m < 4; ++m)
      #pragma unroll
      for (int n = 0; n < 2; ++n)
        #pragma unroll
        for (int k = 0; k < 2; ++k)
          acc[4 + m][2 + n] = __builtin_amdgcn_mfma_f32_16x16x32_f16(af[m][k], bf1[n][k], acc[4 + m][2 + n], 0, 0, 0);
    __builtin_amdgcn_s_setprio(0);
    __builtin_amdgcn_s_barrier(); MEMFENCE;
    // ---- P4: no reads; MFMA quadrant (m4-7, n0-1)
    __builtin_amdgcn_s_setprio(1);
    #pragma unroll
    for (int m = 0; m < 4; ++m)
      #pragma unroll
      for (int n = 0; n < 2; ++n)
        #pragma unroll
        for (int k = 0; k < 2; ++k)
          acc[4 + m][n] = __builtin_amdgcn_mfma_f32_16x16x32_f16(af[m][k], bf0[n][k], acc[4 + m][n], 0, 0, 0);
    __builtin_amdgcn_s_setprio(0);
    // ---- tile boundary: all waves done reading buf[cur]
    __builtin_amdgcn_s_barrier(); MEMFENCE;
    if (kt + 2 < NKT) {                     // stage kt+2 into buf[cur]
      const int ko = (kt + 2) * 64;
      char* aD = (char*)(cur ? As1 : As0);
      char* bD = (char*)(cur ? Bs1 : Bs0);
      #pragma unroll
      for (int i = 0; i < 4; ++i) gload16(aSrcB[i] + ko, aD + i * 8192 + ldsOff);
      #pragma unroll
      for (int i = 0; i < 4; ++i) gload16(bSrcB[i] + ko, bD + i * 8192 + ldsOff);
    }
    if (kt + 1 < NKT) {
      if (kt + 2 < NKT) asm volatile("s_waitcnt vmcnt(8)" ::: "memory");
      else              asm volatile("s_waitcnt vmcnt(0)" ::: "memory");
      __builtin_amdgcn_s_barrier(); MEMFENCE;
    }
    cur ^= 1;
  }

  // ---- epilogue: per-wave LDS region (16KB), swizzled conflict-free, coalesced stores
  float bv[4];
  #pragma unroll
  for (int n = 0; n < 4; ++n)
    bv[n] = (ks == 0) ? bias[e * N + nt * 256 + wc * 64 + n * 16 + ro] : 0.f;
  f16* Ct = smem + wv * 8192;               // [128][64] f16, col-byte ^= ((row>>2)&3)<<5
  #pragma unroll
  for (int m = 0; m < 8; ++m)
    #pragma unroll
    for (int n = 0; n < 4; ++n)
      #pragma unroll
      for (int i = 0; i < 4; ++i) {
        const int row = m * 16 + q4 + i;
        float v = acc[m][n][i] + bv[n];
        if (GELU) v = gelu_fast(v);
        *(f16*)((char*)Ct + row * 128 + ((((n * 16 + ro) * 2)) ^ (((row >> 2) & 3) << 5))) = (f16)v;
      }
  asm volatile("s_waitcnt lgkmcnt(0)" ::: "memory");
  f16* Cp = C + (size_t)ks * pstride;
  const size_t crow0 = (size_t)e * CAPD + mt * 256 + wr * 128;
  const int ccol0 = nt * 256 + wc * 64;
  #pragma unroll
  for (int j = 0; j < 16; ++j) {
    const int idx = j * 64 + lane;
    const int r = idx >> 3, c2 = (idx & 7) * 16;
    f16x8 v = *(const f16x8*)((const char*)Ct + r * 128 + (c2 ^ (((r >> 2) & 3) << 5)));
    *(f16x8*)(Cp + (crow0 + r) * N + ccol0 + (idx & 7) * 8) = v;
  }
}

// ---------------- combine: out[t] = sum_k wslot * (partA[row] + partB[row]) ----------------
__global__ void combine_k(const f16* __restrict__ pA, const f16* __restrict__ pB,
                          const int* __restrict__ eidx, const int* __restrict__ posa,
                          const float* __restrict__ wslot, float* __restrict__ out) {
  const int t = blockIdx.x, tid = threadIdx.x;
  const int s0 = 2 * t, s1 = 2 * t + 1;
  const int e0 = eidx[s0], e1 = eidx[s1];
  int p0 = posa[s0]; p0 = p0 < CAPD - 1 ? p0 : CAPD - 1;
  int p1 = posa[s1]; p1 = p1 < CAPD - 1 ? p1 : CAPD - 1;
  const float g0 = wslot[s0], g1 = wslot[s1];
  const size_t o0 = ((size_t)e0 * CAPD + p0) * DDIM;
  const size_t o1 = ((size_t)e1 * CAPD + p1) * DDIM;
  const f16x2* r0a = (const f16x2*)(pA + o0);
  const f16x2* r0b = (const f16x2*)(pB + o0);
  const f16x2* r1a = (const f16x2*)(pA + o1);
  const f16x2* r1b = (const f16x2*)(pB + o1);
  float2* o = (float2*)(out + (size_t)t * DDIM);
  #pragma unroll
  for (int j = tid; j < DDIM / 2; j += 256) {
    f16x2 a0 = r0a[j], a1 = r0b[j], b0 = r1a[j], b1 = r1b[j];
    o[j] = make_float2(
        g0 * ((float)a0.x + (float)a1.x) + g1 * ((float)b0.x + (float)b1.x),
        g0 * ((float)a0.y + (float)a1.y) + g1 * ((float)b0.y + (float)b1.y));
  }
}

extern "C" void kernel_launch(void* const* d_in, const int* in_sizes, int n_in,
                              void* d_out, int out_size, void* d_ws, size_t ws_size,
                              hipStream_t stream) {
  (void)in_sizes; (void)n_in; (void)out_size; (void)ws_size;
  const float* x  = (const float*)d_in[0];
  const float* rw = (const float*)d_in[1];
  const float* w1 = (const float*)d_in[2];
  const float* b1 = (const float*)d_in[3];
  const float* w2 = (const float*)d_in[4];
  const float* b2 = (const float*)d_in[5];
  float* out = (float*)d_out;

  char* ws = (char*)d_ws;
  size_t off = 0;
  auto alloc = [&](size_t b) { void* p = ws + off; off += (b + 255) & ~(size_t)255; return p; };
  f16* w1t   = (f16*)alloc((size_t)EDIM * DDIM * HDIM * 2);   // (E,H,D)
  f16* w2t   = (f16*)alloc((size_t)EDIM * DDIM * HDIM * 2);   // (E,D,H)
  f16* buf   = (f16*)alloc((size_t)EDIM * CAPD * DDIM * 2);   // (E,CAP,D)
  f16* hbuf  = (f16*)alloc((size_t)EDIM * CAPD * HDIM * 2);   // (E,CAP,H)
  const size_t PSTRIDE = (size_t)EDIM * CAPD * DDIM;
  f16* outeA = (f16*)alloc(PSTRIDE * 2);                       // split-K partial 0
  f16* outeB = (f16*)alloc(PSTRIDE * 2);                       // split-K partial 1 (contiguous)
  int*   eidx   = (int*)alloc(NSLOT * 4);
  int*   posa   = (int*)alloc(NSLOT * 4);
  float* gatesA = (float*)alloc(NSLOT * 4);
  float* wslotA = (float*)alloc(NSLOT * 4);
  int*   cc     = (int*)alloc(32 * EDIM * 4);
  int*   cb     = (int*)alloc(32 * EDIM * 4);
  int*   counts = (int*)alloc(EDIM * 4);
  int*   rowsN  = (int*)alloc(EDIM * 4);
  float* bps    = (float*)alloc(NROUTERBLK * EDIM * 4);
  (void)outeB;

  // weight conversion (independent of routing chain)
  transpose_cvt<<<dim3(HDIM / 64, DDIM / 64, EDIM), 256, 0, stream>>>(w1, w1t, DDIM, HDIM);
  transpose_cvt<<<dim3(DDIM / 64, HDIM / 64, EDIM), 256, 0, stream>>>(w2, w2t, HDIM, DDIM);

  // routing chain
  router_k<<<NROUTERBLK, 256, 0, stream>>>(x, rw, eidx, gatesA, bps);
  count_k<<<32, 256, 0, stream>>>(eidx, cc);
  scan_k<<<1, 256, 0, stream>>>(cc, bps, cb, counts, rowsN, out + (size_t)TDIM * DDIM);
  pos_k<<<32, 256, 0, stream>>>(eidx, gatesA, cb, posa, wslotA);
  scatter_k<<<NSLOT, 64, 0, stream>>>(x, eidx, posa, buf);

  // expert GEMM 1: (E,CAP,D) x (E,D,H) -> GELU -> (E,CAP,H)
  // grid: x=nt, y=e, z=mt (mt slowest => work-first dispatch, balanced CUs)
  gemm256<DDIM, DDIM, HDIM, 1><<<dim3(HDIM / 256, EDIM, CAPD / 256), 512, 0, stream>>>(
      buf, w1t, b1, hbuf, 0, rowsN);

  // expert GEMM 2, split-K=2 in ONE dispatch (y = e + 8*ks, z = mt slowest)
  gemm256<HDIM / 2, HDIM, DDIM, 0><<<dim3(DDIM / 256, EDIM * 2, CAPD / 256), 512, 0, stream>>>(
      hbuf, w2t, b2, outeA, PSTRIDE, rowsN);

  // combine
  combine_k<<<TDIM, 256, 0, stream>>>(outeA, outeA + PSTRIDE, eidx, posa, wslotA, out);
}

// Round 7
// 330.605 us; speedup vs baseline: 1.1262x; 1.1262x over previous
//
#include <hip/hip_runtime.h>
#include <cstdint>
#include <cstddef>

#define TDIM 4096       // B*S tokens
#define DDIM 1024
#define HDIM 4096
#define EDIM 8
#define CAPD 2048
#define NSLOT 8192      // T*K
#define NROUTERBLK 1024

typedef _Float16 f16;
typedef _Float16 f16x2 __attribute__((ext_vector_type(2)));
typedef _Float16 f16x4 __attribute__((ext_vector_type(4)));
typedef _Float16 f16x8 __attribute__((ext_vector_type(8)));
typedef float f32x4 __attribute__((ext_vector_type(4)));

__device__ __forceinline__ void gload16(const void* g, void* l) {
  __builtin_amdgcn_global_load_lds(
      (const __attribute__((address_space(1))) unsigned int*)g,
      (__attribute__((address_space(3))) unsigned int*)l, 16, 0, 0);
}

__device__ __forceinline__ float gelu_fast(float x) {
  float y = 1.5957691216057308f * (x + 0.044715f * x * x * x);
  y = fminf(y, 60.f);
  float e = __expf(y);
  return x * e * __builtin_amdgcn_rcpf(e + 1.f);
}

#define MEMFENCE asm volatile("" ::: "memory")
#define VMCNT(n) asm volatile("s_waitcnt vmcnt(" #n ")" ::: "memory")
#define BAR_ENTER MEMFENCE; __builtin_amdgcn_s_barrier(); \
  asm volatile("s_waitcnt lgkmcnt(0)" ::: "memory")
#define BAR_EXIT __builtin_amdgcn_s_barrier(); MEMFENCE

// ---------------- transpose + f32->f16 convert: src (E,R,C) -> dst (E,C,R) ----------------
__global__ __launch_bounds__(256)
void transpose_cvt(const float* __restrict__ src, f16* __restrict__ dst, int R, int C) {
  __shared__ float tile[64][65];
  const int e = blockIdx.z;
  const int c0 = blockIdx.x * 64, r0 = blockIdx.y * 64;
  const int tid = threadIdx.x;
  const float* s = src + (size_t)e * R * C;
  f16* d = dst + (size_t)e * R * C;
  #pragma unroll
  for (int p = 0; p < 4; ++p) {
    const int row = p * 16 + (tid >> 4);
    const int col = (tid & 15) * 4;
    float4 v = *(const float4*)(s + (size_t)(r0 + row) * C + c0 + col);
    tile[row][col] = v.x; tile[row][col + 1] = v.y;
    tile[row][col + 2] = v.z; tile[row][col + 3] = v.w;
  }
  __syncthreads();
  #pragma unroll
  for (int p = 0; p < 4; ++p) {
    const int crow = p * 16 + (tid >> 4);
    const int q = (tid & 15) * 4;
    f16x4 o;
    #pragma unroll
    for (int j = 0; j < 4; ++j) o[j] = (f16)tile[q + j][crow];
    *(f16x4*)(d + (size_t)(c0 + crow) * R + r0 + q) = o;
  }
}

// ---------------- router ----------------
__global__ void router_k(const float* __restrict__ x, const float* __restrict__ rw,
                         int* __restrict__ eidx, float* __restrict__ gates,
                         float* __restrict__ bps) {
  __shared__ float lrw[EDIM * DDIM];
  __shared__ float wps[4][EDIM];
  const int tid = threadIdx.x, lane = tid & 63, wv = tid >> 6;
  for (int i = tid; i < EDIM * DDIM; i += 256) lrw[i] = rw[i];
  __syncthreads();
  const int t = blockIdx.x * 4 + wv;
  float acc[EDIM];
  #pragma unroll
  for (int e = 0; e < EDIM; ++e) acc[e] = 0.f;
  const float* xr = x + (size_t)t * DDIM;
  #pragma unroll
  for (int j = 0; j < DDIM / 64; ++j) {
    float xv = xr[j * 64 + lane];
    #pragma unroll
    for (int e = 0; e < EDIM; ++e) acc[e] += xv * lrw[e * DDIM + j * 64 + lane];
  }
  #pragma unroll
  for (int off = 32; off >= 1; off >>= 1) {
    #pragma unroll
    for (int e = 0; e < EDIM; ++e) acc[e] += __shfl_xor(acc[e], off);
  }
  float mx = acc[0];
  #pragma unroll
  for (int e = 1; e < EDIM; ++e) mx = fmaxf(mx, acc[e]);
  float p[EDIM], s = 0.f;
  #pragma unroll
  for (int e = 0; e < EDIM; ++e) { p[e] = expf(acc[e] - mx); s += p[e]; }
  float inv = 1.f / s;
  #pragma unroll
  for (int e = 0; e < EDIM; ++e) p[e] *= inv;
  int i1 = 0; float p1 = p[0];
  #pragma unroll
  for (int e = 1; e < EDIM; ++e) if (p[e] > p1) { p1 = p[e]; i1 = e; }
  int i2 = (i1 == 0) ? 1 : 0; float p2 = p[i2];
  #pragma unroll
  for (int e = 0; e < EDIM; ++e) if (e != i1 && p[e] > p2) { p2 = p[e]; i2 = e; }
  float gs = 1.f / (p1 + p2);
  if (lane == 0) {
    eidx[2 * t] = i1; eidx[2 * t + 1] = i2;
    gates[2 * t] = p1 * gs; gates[2 * t + 1] = p2 * gs;
    #pragma unroll
    for (int e = 0; e < EDIM; ++e) wps[wv][e] = p[e];
  }
  __syncthreads();
  if (tid < EDIM)
    bps[blockIdx.x * EDIM + tid] = wps[0][tid] + wps[1][tid] + wps[2][tid] + wps[3][tid];
}

// ---------------- per-chunk expert histogram ----------------
__global__ void count_k(const int* __restrict__ eidx, int* __restrict__ cc) {
  __shared__ int h[EDIM];
  const int tid = threadIdx.x;
  if (tid < EDIM) h[tid] = 0;
  __syncthreads();
  atomicAdd(&h[eidx[blockIdx.x * 256 + tid]], 1);
  __syncthreads();
  if (tid < EDIM) cc[blockIdx.x * EDIM + tid] = h[tid];
}

// ---------------- scan chunks, totals, lb_loss ----------------
__global__ void scan_k(const int* __restrict__ cc, const float* __restrict__ bps,
                       int* __restrict__ cb, int* __restrict__ counts,
                       int* __restrict__ rowsNeeded, float* __restrict__ lb_out) {
  __shared__ float red[32][EDIM];
  __shared__ int cnt_s[EDIM];
  const int tid = threadIdx.x;
  const int e = tid & 7, g = tid >> 3;
  float s = 0.f;
  for (int j = 0; j < 32; ++j) s += bps[(g + 32 * j) * EDIM + e];
  red[g][e] = s;
  __syncthreads();
  for (int st = 16; st >= 1; st >>= 1) {
    if (g < st) red[g][e] += red[g + st][e];
    __syncthreads();
  }
  if (tid < EDIM) {
    int base = 0;
    for (int c = 0; c < 32; ++c) { cb[c * EDIM + tid] = base; base += cc[c * EDIM + tid]; }
    counts[tid] = base;
    rowsNeeded[tid] = base < CAPD ? base : CAPD;
    cnt_s[tid] = base;
  }
  __syncthreads();
  if (tid == 0) {
    float lb = 0.f;
    for (int ee = 0; ee < EDIM; ++ee)
      lb += (red[0][ee] / (float)TDIM) * ((float)cnt_s[ee] / (float)NSLOT);
    lb_out[0] = lb * (float)EDIM;
  }
}

// ---------------- per-slot position via wave ballots (deterministic) ----------------
__global__ void pos_k(const int* __restrict__ eidx, const float* __restrict__ gates,
                      const int* __restrict__ cb, int* __restrict__ posa,
                      float* __restrict__ wslot) {
  __shared__ int wcnt[4][EDIM];
  const int tid = threadIdx.x, lane = tid & 63, wv = tid >> 6;
  const int slot = blockIdx.x * 256 + tid;
  const int e = eidx[slot];
  const unsigned long long below = (1ull << lane) - 1ull;
  int wavepos = 0;
  #pragma unroll
  for (int ee = 0; ee < EDIM; ++ee) {
    unsigned long long m = __ballot(e == ee);
    if (lane == 0) wcnt[wv][ee] = __popcll(m);
    if (e == ee) wavepos = __popcll(m & below);
  }
  __syncthreads();
  int off = 0;
  for (int w = 0; w < wv; ++w) off += wcnt[w][e];
  const int pos = cb[blockIdx.x * EDIM + e] + off + wavepos;
  posa[slot] = pos;
  wslot[slot] = (pos < CAPD) ? gates[slot] : 0.f;
}

// ---------------- scatter token rows -> f16 expert buffers ----------------
__global__ void scatter_k(const float* __restrict__ x, const int* __restrict__ eidx,
                          const int* __restrict__ posa, f16* __restrict__ buf) {
  const int s = blockIdx.x, lane = threadIdx.x;
  const int p = posa[s];
  if (p >= CAPD) return;
  const int e = eidx[s], tok = s >> 1;
  const float4* src = (const float4*)(x + (size_t)tok * DDIM);
  f16x4* dst = (f16x4*)(buf + ((size_t)e * CAPD + p) * DDIM);
  #pragma unroll
  for (int j = 0; j < DDIM / 4 / 64; ++j) {
    float4 v = src[j * 64 + lane];
    f16x4 o; o.x = (f16)v.x; o.y = (f16)v.y; o.z = (f16)v.z; o.w = (f16)v.w;
    dst[j * 64 + lane] = o;
  }
}

// ============ 256x256 f16 MFMA GEMM — faithful m201 8-phase schedule ============
// Per iter: 2 K-tiles (BK=64 each). buf0 holds even tiles, buf1 odd (64KB each:
// A0|A1|B0|B1 halves of 16KB). Each phase: {ds_read frags; stage ONE half-tile
// (2 gload_lds); [vmcnt(4) @P3/P7]; barrier; lgkmcnt(0); setprio1; 16 MFMA;
// setprio0; barrier}. Stage targets are freed exactly >=1 phase earlier:
// A-halves read @P0/P2, B-halves @P0/P1 of their buffer's 4-phase window.
// vmcnt(4)=2 half-tiles outstanding covers every consumer 2 barriers later.
// 1-D grid, e = wg&7 (XCD-affine: one expert per XCD), mt slowest (work-first).
#define LDA(bb, MH) do { \
    const char* base_ = smem + (bb) * 65536 + wr * 16384; \
    _Pragma("unroll") for (int m_ = 0; m_ < 4; ++m_) \
    _Pragma("unroll") for (int k_ = 0; k_ < 2; ++k_) { \
      const int rh_ = (MH) * 64 + m_ * 16 + ro; \
      af[m_][k_] = *(const f16x8*)(base_ + rh_ * 128 + ((k_ * 64 + ko0b) ^ ((rh_ & 7) << 4))); \
    } } while (0)

#define LDB(bb, NH, BF) do { \
    const char* base_ = smem + (bb) * 65536 + (2 + (wc >> 1)) * 16384; \
    _Pragma("unroll") for (int n_ = 0; n_ < 2; ++n_) \
    _Pragma("unroll") for (int k_ = 0; k_ < 2; ++k_) { \
      const int rh_ = (wc & 1) * 64 + (NH) * 32 + n_ * 16 + ro; \
      (BF)[n_][k_] = *(const f16x8*)(base_ + rh_ * 128 + ((k_ * 64 + ko0b) ^ ((rh_ & 7) << 4))); \
    } } while (0)

#define MM16(AM, AN, BF) do { \
    __builtin_amdgcn_s_setprio(1); \
    _Pragma("unroll") for (int m_ = 0; m_ < 4; ++m_) \
    _Pragma("unroll") for (int n_ = 0; n_ < 2; ++n_) \
    _Pragma("unroll") for (int k_ = 0; k_ < 2; ++k_) \
      acc[(AM) + m_][(AN) + n_] = __builtin_amdgcn_mfma_f32_16x16x32_f16( \
          af[m_][k_], (BF)[n_][k_], acc[(AM) + m_][(AN) + n_], 0, 0, 0); \
    __builtin_amdgcn_s_setprio(0); \
  } while (0)

// hh2: 0=A-half0, 1=A-half1, 2=B-half0, 3=B-half1; g = K-tile index
#define STAGE(bb, hh2, g) do { \
    const f16* s_ = (((hh2) < 2) ? (aBase + (size_t)((hh2) * 128) * LD) \
                                 : (bBase + (size_t)(((hh2) - 2) * 128) * LD)) \
                    + (size_t)row0 * LD + (g) * 64 + sw0; \
    char* d_ = smem + (bb) * 65536 + (hh2) * 16384 + wv * 1024; \
    gload16(s_, d_); \
    gload16(s_ + (size_t)64 * LD, d_ + 8192); \
  } while (0)

template<int KLEN, int LD, int N, int GELU, int NT, int NKS>
__global__ __launch_bounds__(512, 1)
void gemm256p(const f16* __restrict__ A, const f16* __restrict__ Bt,
              const float* __restrict__ bias, f16* __restrict__ C, size_t pstride,
              const int* __restrict__ rowsNeeded) {
  constexpr int NI = KLEN / 128;           // iterations, 2 K-tiles each
  __shared__ __align__(128) char smem[131072];
  const int wg = blockIdx.x;
  const int e = wg & 7;
  const int r = wg >> 3;
  const int nt = r % NT;
  const int ks = (r / NT) % NKS;
  const int mt = r / (NT * NKS);
  if (mt * 256 >= rowsNeeded[e]) return;
  const int tid = threadIdx.x, lane = tid & 63, wv = tid >> 6;
  const int wr = wv >> 2, wc = wv & 3;     // 2 x 4 wave grid
  const int ro = lane & 15, q4 = (lane >> 4) * 4;
  const int ko0b = (lane >> 4) * 16;       // k-offset bytes within row
  const f16* aBase = A + ((size_t)e * CAPD + (size_t)mt * 256) * LD + (size_t)ks * KLEN;
  const f16* bBase = Bt + ((size_t)e * N + (size_t)nt * 256) * LD + (size_t)ks * KLEN;
  const int row0 = tid >> 3;               // 0..63 (second gload does row0+64)
  const int sw0 = ((tid & 7) ^ (row0 & 7)) * 8;   // pre-swizzled source col (elements)

  f16x8 af[4][2], bf0[2][2], bf1[2][2];
  f32x4 acc[8][4];
  #pragma unroll
  for (int m = 0; m < 8; ++m)
    #pragma unroll
    for (int n = 0; n < 4; ++n) acc[m][n] = (f32x4){0.f, 0.f, 0.f, 0.f};

  // ---- prologue: tile0 fully + B halves of tile1 (A(tile1) staged at P0/P1)
  STAGE(0, 2, 0); STAGE(0, 3, 0); STAGE(0, 0, 0); STAGE(0, 1, 0);
  STAGE(1, 2, 1); STAGE(1, 3, 1);
  VMCNT(4);                                 // tile0's 8 loads landed
  __builtin_amdgcn_s_barrier(); MEMFENCE;

  #pragma unroll 1
  for (int i = 0; i < NI - 1; ++i) {
    const int g0 = 2 * i;
    // P0: frags A(mh0)+B(nh0) of tile g0; stage A0(g1)
    LDA(0, 0); LDB(0, 0, bf0);
    STAGE(1, 0, g0 + 1);
    BAR_ENTER; MM16(0, 0, bf0); BAR_EXIT;
    // P1: B(nh1); stage A1(g1)
    LDB(0, 1, bf1);
    STAGE(1, 1, g0 + 1);
    BAR_ENTER; MM16(0, 2, bf1); BAR_EXIT;
    // P2: A(mh1); stage B0(g0+2)
    LDA(0, 1);
    STAGE(0, 2, g0 + 2);
    BAR_ENTER; MM16(4, 2, bf1); BAR_EXIT;
    // P3: stage B1(g0+2); checkpoint
    STAGE(0, 3, g0 + 2);
    VMCNT(4);
    BAR_ENTER; MM16(4, 0, bf0); BAR_EXIT;
    // P4: tile g1 (buf1): A(mh0)+B(nh0); stage A0(g0+2)
    LDA(1, 0); LDB(1, 0, bf0);
    STAGE(0, 0, g0 + 2);
    BAR_ENTER; MM16(0, 0, bf0); BAR_EXIT;
    // P5: B(nh1); stage A1(g0+2)
    LDB(1, 1, bf1);
    STAGE(0, 1, g0 + 2);
    BAR_ENTER; MM16(0, 2, bf1); BAR_EXIT;
    // P6: A(mh1); stage B0(g1+2)
    LDA(1, 1);
    STAGE(1, 2, g0 + 3);
    BAR_ENTER; MM16(4, 2, bf1); BAR_EXIT;
    // P7: stage B1(g1+2); checkpoint
    STAGE(1, 3, g0 + 3);
    VMCNT(4);
    BAR_ENTER; MM16(4, 0, bf0); BAR_EXIT;
  }
  // ---- last iter (no lookahead staging beyond its own tile g1)
  {
    LDA(0, 0); LDB(0, 0, bf0);
    STAGE(1, 0, 2 * NI - 1);
    BAR_ENTER; MM16(0, 0, bf0); BAR_EXIT;
    LDB(0, 1, bf1);
    STAGE(1, 1, 2 * NI - 1);
    BAR_ENTER; MM16(0, 2, bf1); BAR_EXIT;
    LDA(0, 1);
    BAR_ENTER; MM16(4, 2, bf1); BAR_EXIT;
    VMCNT(0);
    BAR_ENTER; MM16(4, 0, bf0); BAR_EXIT;
    LDA(1, 0); LDB(1, 0, bf0);
    BAR_ENTER; MM16(0, 0, bf0); BAR_EXIT;
    LDB(1, 1, bf1);
    BAR_ENTER; MM16(0, 2, bf1); BAR_EXIT;
    LDA(1, 1);
    BAR_ENTER; MM16(4, 2, bf1); BAR_EXIT;
    BAR_ENTER; MM16(4, 0, bf0); BAR_EXIT;
  }

  // ---- epilogue: per-wave LDS region (16KB!), swizzled conflict-free, coalesced stores
  float bv[4];
  #pragma unroll
  for (int n = 0; n < 4; ++n)
    bv[n] = (ks == 0) ? bias[e * N + nt * 256 + wc * 64 + n * 16 + ro] : 0.f;
  // FIX(r7): smem is char*, per-wave C-tile is 128x64 f16 = 16384 BYTES. r6 used
  // wv*8192 (a stale f16-pointer stride) -> adjacent waves overlapped -> corruption.
  f16* Ct = (f16*)(smem + wv * 16384);      // [128][64] f16, col-byte ^= ((row>>2)&3)<<5
  #pragma unroll
  for (int m = 0; m < 8; ++m)
    #pragma unroll
    for (int n = 0; n < 4; ++n)
      #pragma unroll
      for (int i = 0; i < 4; ++i) {
        const int row = m * 16 + q4 + i;
        float v = acc[m][n][i] + bv[n];
        if (GELU) v = gelu_fast(v);
        *(f16*)((char*)Ct + row * 128 + ((((n * 16 + ro) * 2)) ^ (((row >> 2) & 3) << 5))) = (f16)v;
      }
  asm volatile("s_waitcnt lgkmcnt(0)" ::: "memory");
  f16* Cp = C + (size_t)ks * pstride;
  const size_t crow0 = (size_t)e * CAPD + mt * 256 + wr * 128;
  const int ccol0 = nt * 256 + wc * 64;
  #pragma unroll
  for (int j = 0; j < 16; ++j) {
    const int idx = j * 64 + lane;
    const int rr = idx >> 3, c2 = (idx & 7) * 16;
    f16x8 v = *(const f16x8*)((const char*)Ct + rr * 128 + (c2 ^ (((rr >> 2) & 3) << 5)));
    *(f16x8*)(Cp + (crow0 + rr) * N + ccol0 + (idx & 7) * 8) = v;
  }
}

// ---------------- combine: out[t] = sum_k wslot * (partA[row] + partB[row]) ----------------
__global__ void combine_k(const f16* __restrict__ pA, const f16* __restrict__ pB,
                          const int* __restrict__ eidx, const int* __restrict__ posa,
                          const float* __restrict__ wslot, float* __restrict__ out) {
  const int t = blockIdx.x, tid = threadIdx.x;
  const int s0 = 2 * t, s1 = 2 * t + 1;
  const int e0 = eidx[s0], e1 = eidx[s1];
  int p0 = posa[s0]; p0 = p0 < CAPD - 1 ? p0 : CAPD - 1;
  int p1 = posa[s1]; p1 = p1 < CAPD - 1 ? p1 : CAPD - 1;
  const float g0 = wslot[s0], g1 = wslot[s1];
  const size_t o0 = ((size_t)e0 * CAPD + p0) * DDIM;
  const size_t o1 = ((size_t)e1 * CAPD + p1) * DDIM;
  const f16x2* r0a = (const f16x2*)(pA + o0);
  const f16x2* r0b = (const f16x2*)(pB + o0);
  const f16x2* r1a = (const f16x2*)(pA + o1);
  const f16x2* r1b = (const f16x2*)(pB + o1);
  float2* o = (float2*)(out + (size_t)t * DDIM);
  #pragma unroll
  for (int j = tid; j < DDIM / 2; j += 256) {
    f16x2 a0 = r0a[j], a1 = r0b[j], b0 = r1a[j], b1 = r1b[j];
    o[j] = make_float2(
        g0 * ((float)a0.x + (float)a1.x) + g1 * ((float)b0.x + (float)b1.x),
        g0 * ((float)a0.y + (float)a1.y) + g1 * ((float)b0.y + (float)b1.y));
  }
}

extern "C" void kernel_launch(void* const* d_in, const int* in_sizes, int n_in,
                              void* d_out, int out_size, void* d_ws, size_t ws_size,
                              hipStream_t stream) {
  (void)in_sizes; (void)n_in; (void)out_size; (void)ws_size;
  const float* x  = (const float*)d_in[0];
  const float* rw = (const float*)d_in[1];
  const float* w1 = (const float*)d_in[2];
  const float* b1 = (const float*)d_in[3];
  const float* w2 = (const float*)d_in[4];
  const float* b2 = (const float*)d_in[5];
  float* out = (float*)d_out;

  char* ws = (char*)d_ws;
  size_t off = 0;
  auto alloc = [&](size_t b) { void* p = ws + off; off += (b + 255) & ~(size_t)255; return p; };
  f16* w1t   = (f16*)alloc((size_t)EDIM * DDIM * HDIM * 2);   // (E,H,D)
  f16* w2t   = (f16*)alloc((size_t)EDIM * DDIM * HDIM * 2);   // (E,D,H)
  f16* buf   = (f16*)alloc((size_t)EDIM * CAPD * DDIM * 2);   // (E,CAP,D)
  f16* hbuf  = (f16*)alloc((size_t)EDIM * CAPD * HDIM * 2);   // (E,CAP,H)
  const size_t PSTRIDE = (size_t)EDIM * CAPD * DDIM;
  f16* outeA = (f16*)alloc(PSTRIDE * 2);                       // split-K partial 0
  f16* outeB = (f16*)alloc(PSTRIDE * 2);                       // split-K partial 1 (contiguous)
  int*   eidx   = (int*)alloc(NSLOT * 4);
  int*   posa   = (int*)alloc(NSLOT * 4);
  float* gatesA = (float*)alloc(NSLOT * 4);
  float* wslotA = (float*)alloc(NSLOT * 4);
  int*   cc     = (int*)alloc(32 * EDIM * 4);
  int*   cb     = (int*)alloc(32 * EDIM * 4);
  int*   counts = (int*)alloc(EDIM * 4);
  int*   rowsN  = (int*)alloc(EDIM * 4);
  float* bps    = (float*)alloc(NROUTERBLK * EDIM * 4);
  (void)outeB;

  // weight conversion (independent of routing chain)
  transpose_cvt<<<dim3(HDIM / 64, DDIM / 64, EDIM), 256, 0, stream>>>(w1, w1t, DDIM, HDIM);
  transpose_cvt<<<dim3(DDIM / 64, HDIM / 64, EDIM), 256, 0, stream>>>(w2, w2t, HDIM, DDIM);

  // routing chain
  router_k<<<NROUTERBLK, 256, 0, stream>>>(x, rw, eidx, gatesA, bps);
  count_k<<<32, 256, 0, stream>>>(eidx, cc);
  scan_k<<<1, 256, 0, stream>>>(cc, bps, cb, counts, rowsN, out + (size_t)TDIM * DDIM);
  pos_k<<<32, 256, 0, stream>>>(eidx, gatesA, cb, posa, wslotA);
  scatter_k<<<NSLOT, 64, 0, stream>>>(x, eidx, posa, buf);

  // expert GEMM 1: (E,CAP,D) x (E,D,H) -> GELU -> (E,CAP,H)
  // 1-D grid: wg = e + 8*(nt + 16*mt)  (e fastest -> XCD-affine; mt slowest)
  gemm256p<DDIM, DDIM, HDIM, 1, 16, 1><<<1024, 512, 0, stream>>>(
      buf, w1t, b1, hbuf, 0, rowsN);

  // expert GEMM 2, split-K=2 in ONE dispatch: wg = e + 8*(nt + 4*(ks + 2*mt))
  gemm256p<HDIM / 2, HDIM, DDIM, 0, 4, 2><<<512, 512, 0, stream>>>(
      hbuf, w2t, b2, outeA, PSTRIDE, rowsN);

  // combine
  combine_k<<<TDIM, 256, 0, stream>>>(outeA, outeA + PSTRIDE, eidx, posa, wslotA, out);
}